// Round 7
// baseline (669.122 us; speedup 1.0000x reference)
//
#include <hip/hip_runtime.h>
#include <cstdint>
#include <cstddef>

// ---- problem dims ----
#define B_ 4
#define T_ 8192
#define W_ 1024
#define L_ 1024
#define H_ 8
#define D_ 128
#define TW_ 4
#define BT_ (B_*T_)        // 32768 rows
#define CHUNK_ 64
#define NCH_ (T_/CHUNK_)   // 128 chunks

typedef __bf16 bf16_t;
typedef __bf16 bf16x8 __attribute__((ext_vector_type(8)));
typedef __bf16 bf16x4 __attribute__((ext_vector_type(4)));
typedef float  f32x4  __attribute__((ext_vector_type(4)));

__device__ __forceinline__ float  bf2f(bf16_t x){ return (float)x; }
__device__ __forceinline__ bf16_t f2bf(float x){ return (bf16_t)x; }

// raw-instruction transcendentals (avoid libm IEEE fixup sequences; outputs are bf16)
__device__ __forceinline__ float rcp_ (float x){ return __builtin_amdgcn_rcpf(x); }
__device__ __forceinline__ float sqrt_(float x){ return __builtin_amdgcn_sqrtf(x); }
__device__ __forceinline__ float exp2_(float x){ return __builtin_amdgcn_exp2f(x); }
__device__ __forceinline__ float log2_(float x){ return __builtin_amdgcn_logf(x); }
#define LOG2E_ 1.4426950408889634f

__device__ __forceinline__ float sigmoid_fast(float z){
  return rcp_(1.0f + exp2_(-LOG2E_*z));
}
__device__ __forceinline__ float softplus_fast(float x){
  return (x > 15.0f) ? x : 0.6931471805599453f * log2_(1.0f + exp2_(LOG2E_*x));
}
__device__ __forceinline__ float gelu_fast(float z){
  float g = 0.7978845608028654f*(z + 0.044715f*z*z*z);
  float e = exp2_(-2.8853900817779268f*fabsf(g));   // exp(-2|g|)
  float th = (1.0f - e)*rcp_(1.0f + e);
  th = copysignf(th, g);
  return 0.5f*z*(1.0f + th);
}

// ---- async global->LDS staging: 128-row x 32-col bf16 tile, row-major, no pad ----
__device__ __forceinline__ void stage16(const bf16_t* g, bf16_t* l){
  __builtin_amdgcn_global_load_lds((const __attribute__((address_space(1))) void*)g,
                                   (__attribute__((address_space(3))) void*)l, 16, 0, 0);
}
__device__ __forceinline__ void stage_tile(const bf16_t* __restrict__ gbase, int ldg,
                                           bf16_t* lds, int wave, int lane){
  #pragma unroll
  for (int c2 = 0; c2 < 2; ++c2){
    int chunk = wave*2 + c2;
    int row = chunk*16 + (lane >> 2);
    int col = (lane & 3)*8;
    stage16(gbase + (size_t)row*ldg + col, lds + chunk*512 + lane*8);
  }
}

// ---- f32 -> bf16 bulk convert (for x) ----
__global__ void __launch_bounds__(256) cvt_kernel(const float* __restrict__ in,
                                                  bf16_t* __restrict__ out, int n8){
  int g = blockIdx.x*256 + threadIdx.x;
  if (g >= n8) return;
  f32x4 a = *(const f32x4*)(in + (size_t)g*8);
  f32x4 b = *(const f32x4*)(in + (size_t)g*8 + 4);
  bf16x8 o;
  #pragma unroll
  for (int e=0;e<4;e++){ o[e] = f2bf(a[e]); o[4+e] = f2bf(b[e]); }
  *(bf16x8*)(out + (size_t)g*8) = o;
}

// ---- batched transpose f32 -> bf16: out[b][c][r] = (bf16)in[b][r][c] ----
__global__ void __launch_bounds__(256) transpose_f2b(const float* __restrict__ in,
                                                     bf16_t* __restrict__ out, int R, int C){
  __shared__ float tile[32][33];
  size_t mb = (size_t)blockIdx.z * R * C;
  int c0 = blockIdx.x*32, r0 = blockIdx.y*32;
  int tx = threadIdx.x, ty = threadIdx.y;
  #pragma unroll
  for (int i = ty; i < 32; i += 8)
    tile[i][tx] = in[mb + (size_t)(r0+i)*C + c0 + tx];
  __syncthreads();
  #pragma unroll
  for (int i = ty; i < 32; i += 8)
    out[mb + (size_t)(c0+i)*R + r0 + tx] = f2bf(tile[tx][i]);
}

// ---- single-output 128x128-tile GEMM, m97 structure, 3 waves/SIMD register cap.
//      Single-acc (64 AGPR) + <=106 VGPR -> 3 blocks/CU: co-resident blocks in
//      offset phases cover each other's barrier drain (m114 overlap model).
//      ACT: 0 = bf16 linear+bias, 1 = bf16 gelu(.+bias), 2 = f32 linear+bias.
template<int ACT>
__global__ void __launch_bounds__(256,3) gemm128(
    const bf16_t* __restrict__ A, const bf16_t* __restrict__ Bt, // Bt: [N=1024][K=1024]
    const float* __restrict__ bias, void* __restrict__ outp)
{
  __shared__ __align__(16) bf16_t As[128*32];
  __shared__ __align__(16) bf16_t Bs[128*32];
  __shared__ __align__(16) bf16_t scr_g[4][1280];   // per-wave epilogue bounce
  const int K = 1024;
  int tid = threadIdx.x, wave = tid>>6, lane = tid&63;
  int wm = wave>>1, wn = wave&1, q = lane>>4, ml = lane&15;
  int lin = blockIdx.x;                    // 2048 blocks, bijective XCD swizzle
  int nl = (lin & 7)*256 + (lin >> 3);
  int bm = nl >> 3, j = nl & 7;
  const bf16_t* Bp = Bt + (size_t)j*128*K;
  f32x4 acc[4][4] = {};
  for (int k0 = 0; k0 < K; k0 += 32){
    stage_tile(A + (size_t)bm*128*K + k0, K, As, wave, lane);
    stage_tile(Bp + k0, K, Bs, wave, lane);
    __syncthreads();
    bf16x8 af[4], bv[4];
    #pragma unroll
    for (int i=0;i<4;i++) af[i] = *(const bf16x8*)(As + (wm*64 + i*16 + ml)*32 + q*8);
    #pragma unroll
    for (int i=0;i<4;i++) bv[i] = *(const bf16x8*)(Bs + (wn*64 + i*16 + ml)*32 + q*8);
    #pragma unroll
    for (int i=0;i<4;i++)
      #pragma unroll
      for (int n=0;n<4;n++)
        acc[i][n] = __builtin_amdgcn_mfma_f32_16x16x32_bf16(af[i], bv[n], acc[i][n], 0,0,0);
    __syncthreads();
  }
  float bb[4];
  #pragma unroll
  for (int n=0;n<4;n++) bb[n] = bias[j*128 + wn*64 + n*16 + ml];
  int rrow = lane>>2, cgp = lane&3;
  size_t mbase = (size_t)bm*128 + wm*64;
  if (ACT == 2){
    float* scrf = (float*)scr_g[wave];          // 16 rows x stride 20 f32 (1280B of 2560B)
    #pragma unroll
    for (int i=0;i<4;i++){
      size_t grow = mbase + i*16 + rrow;
      #pragma unroll
      for (int n=0;n<4;n++){
        #pragma unroll
        for (int r=0;r<4;r++) scrf[(q*4+r)*20 + ml] = acc[i][n][r] + bb[n];
        f32x4 ov = *(const f32x4*)(scrf + rrow*20 + cgp*4);
        *(f32x4*)((float*)outp + grow*1024 + j*128 + wn*64 + n*16 + cgp*4) = ov;
      }
    }
  } else {
    bf16_t* s0 = scr_g[wave];
    bf16_t* s1 = s0 + 640;
    #pragma unroll
    for (int i=0;i<4;i++){
      size_t grow = mbase + i*16 + rrow;
      int gc = j*128 + wn*64 + cgp*8;
      #pragma unroll
      for (int n=0;n<4;n++){
        bf16_t* sp = (n<2) ? s0 : s1;
        #pragma unroll
        for (int r=0;r<4;r++){
          float v = acc[i][n][r] + bb[n];
          if (ACT==1) v = gelu_fast(v);
          sp[(q*4+r)*40 + (n&1)*16 + ml] = f2bf(v);
        }
      }
      bf16x8 v0 = *(const bf16x8*)(s0 + rrow*40 + cgp*8);
      bf16x8 v1 = *(const bf16x8*)(s1 + rrow*40 + cgp*8);
      *(bf16x8*)((bf16_t*)outp + grow*1024 + gc)      = v0;
      *(bf16x8*)((bf16_t*)outp + grow*1024 + gc + 32) = v1;
    }
  }
}

// ---- K3: conv(U0) fused + per-head gate GEMMs + RG-LRU prep + FUSED scan1.
//      Each wave's output quadrant = one 64-row chunk x 64 cols; the chunk
//      summary (A = prod a, B = scan tail) is computed in-register via
//      4-row serial runs + ordered q-butterfly (__shfl_xor) + serial i-chain.
__global__ void __launch_bounds__(256,2) gate_kernel(
    const bf16_t* __restrict__ U0,
    const bf16_t* __restrict__ igTw, const bf16_t* __restrict__ agTw, // [H][e=128][d=128]
    const float* __restrict__ igb,  const float* __restrict__ agb,    // [H*128]
    const float* __restrict__ a_param,
    const float* __restrict__ conv_w, const float* __restrict__ conv_b,
    const int* __restrict__ segpos,
    bf16_t* __restrict__ XN, bf16_t* __restrict__ L2A,
    float* __restrict__ Aarr, float* __restrict__ Barr)
{
  __shared__ __align__(16) bf16_t As[4*128*32];     // conv output, full 128x128 tile
  __shared__ __align__(16) bf16_t scr_g[4][2560];   // per-wave: xn0,xn1,la0,la1 (640 each)
  int tid = threadIdx.x, wave = tid>>6, lane = tid&63;
  int wm = wave>>1, wn = wave&1, q = lane>>4, ml = lane&15;
  int bm = blockIdx.x, h = blockIdx.y;

  // ---- Phase 0: conv(U0) -> As (each thread: 8 rows x 8 cols, sliding window) ----
  {
    int cg = tid & 15, rg = tid >> 4;
    int col = cg*8;                 // within head slice
    int kcc = col >> 5, c32 = col & 31;
    const bf16_t* up = U0 + ((size_t)bm*128 + (size_t)rg*8)*L_ + h*128 + col;
    f32x4 wta[4], wtb[4];
    #pragma unroll
    for (int s=0;s<4;s++){          // tap delay s uses weight conv_w[3-s]
      wta[s] = *(const f32x4*)(conv_w + (size_t)(3-s)*L_ + h*128 + col);
      wtb[s] = *(const f32x4*)(conv_w + (size_t)(3-s)*L_ + h*128 + col + 4);
    }
    f32x4 cba = *(const f32x4*)(conv_b + h*128 + col);
    f32x4 cbb = *(const f32x4*)(conv_b + h*128 + col + 4);
    bool first = (bm & 63) == 0;    // tile starts at segment position 0
    int r0 = rg*8;
    bf16x8 zero8 = {};
    bf16x8 m1 = (!first || r0 >= 1) ? *(const bf16x8*)(up - 1*L_) : zero8;
    bf16x8 m2 = (!first || r0 >= 2) ? *(const bf16x8*)(up - 2*L_) : zero8;
    bf16x8 m3 = (!first || r0 >= 3) ? *(const bf16x8*)(up - 3*L_) : zero8;
    #pragma unroll
    for (int r=0;r<8;r++){
      bf16x8 cur = *(const bf16x8*)(up + (size_t)r*L_);
      bf16x8 ov;
      #pragma unroll
      for (int e=0;e<4;e++){
        float v0 = cba[e] + bf2f(cur[e])*wta[0][e] + bf2f(m1[e])*wta[1][e]
                          + bf2f(m2[e])*wta[2][e] + bf2f(m3[e])*wta[3][e];
        float v1 = cbb[e] + bf2f(cur[4+e])*wtb[0][e] + bf2f(m1[4+e])*wtb[1][e]
                          + bf2f(m2[4+e])*wtb[2][e] + bf2f(m3[4+e])*wtb[3][e];
        ov[e] = f2bf(v0); ov[4+e] = f2bf(v1);
      }
      *(bf16x8*)(As + kcc*4096 + (size_t)(r0+r)*32 + c32) = ov;
      m3 = m2; m2 = m1; m1 = cur;
    }
  }
  __syncthreads();

  // ---- MFMA: A from LDS, B fragments direct from L2-resident weights ----
  const bf16_t* igp = igTw + (size_t)h*D_*D_;
  const bf16_t* agp = agTw + (size_t)h*D_*D_;
  f32x4 ax[4][4] = {}, aa[4][4] = {};
  #pragma unroll
  for (int kc=0; kc<4; ++kc){
    bf16x8 af[4], bx_[4], ba_[4];
    #pragma unroll
    for (int i=0;i<4;i++) af[i]  = *(const bf16x8*)(As + kc*4096 + (wm*64 + i*16 + ml)*32 + q*8);
    #pragma unroll
    for (int n=0;n<4;n++) bx_[n] = *(const bf16x8*)(igp + (size_t)(wn*64 + n*16 + ml)*128 + kc*32 + q*8);
    #pragma unroll
    for (int n=0;n<4;n++) ba_[n] = *(const bf16x8*)(agp + (size_t)(wn*64 + n*16 + ml)*128 + kc*32 + q*8);
    #pragma unroll
    for (int i=0;i<4;i++)
      #pragma unroll
      for (int n=0;n<4;n++){
        ax[i][n] = __builtin_amdgcn_mfma_f32_16x16x32_bf16(af[i], bx_[n], ax[i][n], 0,0,0);
        aa[i][n] = __builtin_amdgcn_mfma_f32_16x16x32_bf16(af[i], ba_[n], aa[i][n], 0,0,0);
      }
  }

  // ---- Epilogue: gates + RG-LRU prep, paired full-line stores, chunk-scan accum ----
  bf16_t* sx0 = scr_g[wave];
  bf16_t* sx1 = sx0 + 640;
  bf16_t* sa0 = sx0 + 1280;
  bf16_t* sa1 = sx0 + 1920;
  int rrow = lane>>2, cgp = lane&3;
  size_t mbase = (size_t)bm*128 + wm*64;
  float bb_x[4], bb_a[4], spa4[4]; int kc4[4], ci4[4];
  #pragma unroll
  for (int n=0;n<4;n++){
    int e = wn*64 + n*16 + ml;
    int l = h*D_ + e;
    bb_x[n] = igb[l]; bb_a[n] = agb[l]; spa4[n] = softplus_fast(a_param[l]);
    kc4[n] = e>>5; ci4[n] = e&31;
  }
  float runS[4][4], runB[4][4];   // per-thread 4-row run summaries [i][n]
  #pragma unroll
  for (int i=0;i<4;i++){
    #pragma unroll
    for (int r=0;r<4;r++){
      int rl = wm*64 + i*16 + q*4 + r;
      size_t row = mbase + i*16 + q*4 + r;
      bool reset = (segpos[row] == 0);
      #pragma unroll
      for (int n=0;n<4;n++){
        float uval = bf2f(As[kc4[n]*4096 + rl*32 + ci4[n]]);
        float gx = sigmoid_fast(ax[i][n][r] + bb_x[n]);
        float ga = sigmoid_fast(aa[i][n][r] + bb_a[n]);
        float l2a = -11.541560327111707f * ga * spa4[n];     // -8*log2(e)*ga*spa
        float mult = reset ? 1.0f : sqrt_(fmaxf(0.0f, 1.0f - exp2_(2.0f*l2a)));
        bf16_t xnv = f2bf(uval * gx * mult);
        bf16_t lav = f2bf(reset ? -1e30f : l2a);
        int so = (q*4+r)*40 + (n&1)*16 + ml;
        if (n < 2){ sx0[so] = xnv; sa0[so] = lav; }
        else      { sx1[so] = xnv; sa1[so] = lav; }
        // scan-run accumulate (bf16-rounded values: identical to re-reading L2A/XN)
        float lf = bf2f(lav), xf = bf2f(xnv);
        if (r == 0){ runS[i][n] = lf;  runB[i][n] = xf; }
        else       { runS[i][n] += lf; runB[i][n] = exp2_(lf)*runB[i][n] + xf; }
      }
    }
    size_t grow = mbase + i*16 + rrow;
    int gc = h*D_ + wn*64 + cgp*8;
    bf16x8 xv0 = *(const bf16x8*)(sx0 + rrow*40 + cgp*8);
    bf16x8 xv1 = *(const bf16x8*)(sx1 + rrow*40 + cgp*8);
    *(bf16x8*)(XN + grow*L_ + gc)      = xv0;
    *(bf16x8*)(XN + grow*L_ + gc + 32) = xv1;
    bf16x8 av0 = *(const bf16x8*)(sa0 + rrow*40 + cgp*8);
    bf16x8 av1 = *(const bf16x8*)(sa1 + rrow*40 + cgp*8);
    *(bf16x8*)(L2A + grow*L_ + gc)      = av0;
    *(bf16x8*)(L2A + grow*L_ + gc + 32) = av1;
  }

  // ---- fused scan1: ordered butterfly across q (lane bits 4,5), serial i-chain ----
  int u16 = lane & 16, u32b = lane & 32;
  float totS[4], totB[4];
  #pragma unroll
  for (int n=0;n<4;n++){
    #pragma unroll
    for (int i=0;i<4;i++){
      float s = runS[i][n], b = runB[i][n];
      float s2 = __shfl_xor(s, 16), b2 = __shfl_xor(b, 16);
      float b1 = u16 ? (exp2_(s)*b2 + b) : (exp2_(s2)*b + b2);   // ordered combine
      float s1 = s + s2;
      float s3 = __shfl_xor(s1, 32), b3 = __shfl_xor(b1, 32);
      float bb = u32b ? (exp2_(s1)*b3 + b1) : (exp2_(s3)*b1 + b3);
      float ss = s1 + s3;
      if (i == 0){ totS[n] = ss; totB[n] = bb; }
      else { totB[n] = exp2_(ss)*totB[n] + bb; totS[n] += ss; }
    }
  }
  if (lane < 16){
    int bb_ = bm >> 6;                   // batch
    int cc_ = (bm & 63)*2 + wm;          // chunk within batch
    size_t ci = ((size_t)bb_*NCH_ + cc_)*L_ + h*D_ + wn*64 + ml;
    #pragma unroll
    for (int n=0;n<4;n++){
      Aarr[ci + n*16] = exp2_(totS[n]);
      Barr[ci + n*16] = totB[n];
    }
  }
}

// ---- K5/K6: inter-chunk scan + elementwise apply ----
__global__ void __launch_bounds__(64) scan2_kernel(const float* __restrict__ Aarr,
    const float* __restrict__ Barr, float* __restrict__ Carr)
{
  int l4 = blockIdx.x*64 + threadIdx.x;  // quad index 0..255
  int b = blockIdx.y;
  f32x4 h = {0.f, 0.f, 0.f, 0.f};
  #pragma unroll 4
  for (int c = 0; c < NCH_; ++c){
    size_t ci = ((size_t)b*NCH_ + c)*L_ + (size_t)l4*4;
    f32x4 a  = *(const f32x4*)(Aarr + ci);
    f32x4 bb = *(const f32x4*)(Barr + ci);
    *(f32x4*)(Carr + ci) = h;
    #pragma unroll
    for (int e=0;e<4;e++) h[e] = a[e]*h[e] + bb[e];
  }
}

// one chunk per 256-thread block, 4 channels/thread -> 512 blocks, 8 waves/CU of MLP
__global__ void __launch_bounds__(256) scan3_kernel(const bf16_t* __restrict__ L2A,
    const bf16_t* __restrict__ XN, const bf16_t* __restrict__ Y,
    const float* __restrict__ Carr, bf16_t* __restrict__ HY)
{
  int l = threadIdx.x*4;
  int c = blockIdx.y, b = blockIdx.z;
  size_t base = ((size_t)b*T_ + (size_t)c*CHUNK_)*L_ + l;
  size_t ci = ((size_t)b*NCH_ + c)*L_ + l;
  f32x4 hv = *(const f32x4*)(Carr + ci);
  float h[4];
  #pragma unroll
  for (int e=0;e<4;e++) h[e] = hv[e];
  #pragma unroll 4
  for (int t = 0; t < CHUNK_; ++t){
    bf16x4 la = *(const bf16x4*)(L2A + base + (size_t)t*L_);
    bf16x4 xv = *(const bf16x4*)(XN  + base + (size_t)t*L_);
    bf16x4 yv = *(const bf16x4*)(Y   + base + (size_t)t*L_);
    bf16x4 o;
    #pragma unroll
    for (int e=0;e<4;e++){
      h[e] = exp2_(bf2f(la[e]))*h[e] + bf2f(xv[e]);
      o[e] = f2bf(h[e]*bf2f(yv[e]));
    }
    *(bf16x4*)(HY + base + (size_t)t*L_) = o;
  }
}

extern "C" void kernel_launch(void* const* d_in, const int* in_sizes, int n_in,
                              void* d_out, int out_size, void* d_ws, size_t ws_size,
                              hipStream_t stream)
{
  (void)in_sizes; (void)n_in; (void)out_size;
  const float* x      = (const float*)d_in[0];
  const int*   segpos = (const int*)  d_in[1];
  const float* Wy     = (const float*)d_in[2];
  const float* by     = (const float*)d_in[3];
  const float* Wx     = (const float*)d_in[4];
  const float* bx     = (const float*)d_in[5];
  const float* conv_w = (const float*)d_in[6];
  const float* conv_b = (const float*)d_in[7];
  const float* a_par  = (const float*)d_in[8];
  const float* igw    = (const float*)d_in[9];
  const float* igb    = (const float*)d_in[10];
  const float* agw    = (const float*)d_in[11];
  const float* agb    = (const float*)d_in[12];
  const float* Wout   = (const float*)d_in[13];
  const float* bout   = (const float*)d_in[14];
  float* out = (float*)d_out;

  char* ws = (char*)d_ws;
  size_t off = 0;
  auto alloc = [&](size_t bytes)->void*{ void* p = ws + off; off += (bytes + 255) & ~(size_t)255; return p; };
  bf16_t* Xbf  = (bf16_t*)alloc((size_t)BT_*W_*2);      // x in bf16; dead after X-GEMMs
  bf16_t* WyT  = (bf16_t*)alloc((size_t)W_*L_*2);
  bf16_t* WxT  = (bf16_t*)alloc((size_t)W_*L_*2);
  bf16_t* WoT  = (bf16_t*)alloc((size_t)L_*W_*2);
  bf16_t* igTw = (bf16_t*)alloc((size_t)H_*D_*D_*2);
  bf16_t* agTw = (bf16_t*)alloc((size_t)H_*D_*D_*2);
  bf16_t* Y    = (bf16_t*)alloc((size_t)BT_*L_*2);
  bf16_t* U0   = (bf16_t*)alloc((size_t)BT_*L_*2);      // reused as HY after scan3
  bf16_t* XN   = (bf16_t*)alloc((size_t)BT_*L_*2);
  float*  Aarr = (float*) alloc((size_t)B_*NCH_*L_*4);
  float*  Barr = (float*) alloc((size_t)B_*NCH_*L_*4);
  float*  Carr = (float*) alloc((size_t)B_*NCH_*L_*4);
  if (ws_size < off) return;  // insufficient workspace: output stays zero (diagnosable)

  bf16_t* L2A = Xbf;   // alias: Xbf dead once both X-GEMMs complete, before gate_kernel
  bf16_t* HY  = U0;    // alias: U0 last read by gate_kernel (conv fused there)

  cvt_kernel<<<dim3(BT_*W_/8/256), 256, 0, stream>>>(x, Xbf, BT_*W_/8);

  dim3 tb(32, 8);
  transpose_f2b<<<dim3(32,32,1), tb, 0, stream>>>(Wy,   WyT, 1024, 1024);
  transpose_f2b<<<dim3(32,32,1), tb, 0, stream>>>(Wx,   WxT, 1024, 1024);
  transpose_f2b<<<dim3(32,32,1), tb, 0, stream>>>(Wout, WoT, 1024, 1024);
  transpose_f2b<<<dim3(4,4,H_),  tb, 0, stream>>>(igw,  igTw, 128, 128);
  transpose_f2b<<<dim3(4,4,H_),  tb, 0, stream>>>(agw,  agTw, 128, 128);

  gemm128<1><<<dim3(2048), 256, 0, stream>>>(Xbf, WyT, by, (void*)Y);
  gemm128<0><<<dim3(2048), 256, 0, stream>>>(Xbf, WxT, bx, (void*)U0);
  gate_kernel<<<dim3(BT_/128, H_), 256, 0, stream>>>(U0, igTw, agTw, igb, agb, a_par,
                                                     conv_w, conv_b, segpos, XN, L2A,
                                                     Aarr, Barr);
  scan2_kernel<<<dim3(4, B_), 64, 0, stream>>>(Aarr, Barr, Carr);
  scan3_kernel<<<dim3(1, NCH_, B_), 256, 0, stream>>>(L2A, XN, Y, Carr, HY);
  gemm128<2><<<dim3(2048), 256, 0, stream>>>(HY, WoT, bout, (void*)out);
}

// Round 8
// 648.897 us; speedup vs baseline: 1.0312x; 1.0312x over previous
//
#include <hip/hip_runtime.h>
#include <cstdint>
#include <cstddef>

// ---- problem dims ----
#define B_ 4
#define T_ 8192
#define W_ 1024
#define L_ 1024
#define H_ 8
#define D_ 128
#define TW_ 4
#define BT_ (B_*T_)        // 32768 rows
#define CHUNK_ 64
#define NCH_ (T_/CHUNK_)   // 128 chunks

typedef __bf16 bf16_t;
typedef __bf16 bf16x8 __attribute__((ext_vector_type(8)));
typedef __bf16 bf16x4 __attribute__((ext_vector_type(4)));
typedef float  f32x4  __attribute__((ext_vector_type(4)));

__device__ __forceinline__ float  bf2f(bf16_t x){ return (float)x; }
__device__ __forceinline__ bf16_t f2bf(float x){ return (bf16_t)x; }

// raw-instruction transcendentals (avoid libm IEEE fixup sequences; outputs are bf16)
__device__ __forceinline__ float rcp_ (float x){ return __builtin_amdgcn_rcpf(x); }
__device__ __forceinline__ float sqrt_(float x){ return __builtin_amdgcn_sqrtf(x); }
__device__ __forceinline__ float exp2_(float x){ return __builtin_amdgcn_exp2f(x); }
__device__ __forceinline__ float log2_(float x){ return __builtin_amdgcn_logf(x); }
#define LOG2E_ 1.4426950408889634f

__device__ __forceinline__ float sigmoid_fast(float z){
  return rcp_(1.0f + exp2_(-LOG2E_*z));
}
__device__ __forceinline__ float softplus_fast(float x){
  return (x > 15.0f) ? x : 0.6931471805599453f * log2_(1.0f + exp2_(LOG2E_*x));
}
__device__ __forceinline__ float gelu_fast(float z){
  float g = 0.7978845608028654f*(z + 0.044715f*z*z*z);
  float e = exp2_(-2.8853900817779268f*fabsf(g));   // exp(-2|g|)
  float th = (1.0f - e)*rcp_(1.0f + e);
  th = copysignf(th, g);
  return 0.5f*z*(1.0f + th);
}

// ---- async global->LDS staging: 128-row x 32-col bf16 tile, row-major, no pad ----
__device__ __forceinline__ void stage16(const bf16_t* g, bf16_t* l){
  __builtin_amdgcn_global_load_lds((const __attribute__((address_space(1))) void*)g,
                                   (__attribute__((address_space(3))) void*)l, 16, 0, 0);
}
__device__ __forceinline__ void stage_tile(const bf16_t* __restrict__ gbase, int ldg,
                                           bf16_t* lds, int wave, int lane){
  #pragma unroll
  for (int c2 = 0; c2 < 2; ++c2){
    int chunk = wave*2 + c2;
    int row = chunk*16 + (lane >> 2);
    int col = (lane & 3)*8;
    stage16(gbase + (size_t)row*ldg + col, lds + chunk*512 + lane*8);
  }
}

// ---- f32 -> bf16 bulk convert (for x) ----
__global__ void __launch_bounds__(256) cvt_kernel(const float* __restrict__ in,
                                                  bf16_t* __restrict__ out, int n8){
  int g = blockIdx.x*256 + threadIdx.x;
  if (g >= n8) return;
  f32x4 a = *(const f32x4*)(in + (size_t)g*8);
  f32x4 b = *(const f32x4*)(in + (size_t)g*8 + 4);
  bf16x8 o;
  #pragma unroll
  for (int e=0;e<4;e++){ o[e] = f2bf(a[e]); o[4+e] = f2bf(b[e]); }
  *(bf16x8*)(out + (size_t)g*8) = o;
}

// ---- batched transpose f32 -> bf16: out[b][c][r] = (bf16)in[b][r][c] ----
__global__ void __launch_bounds__(256) transpose_f2b(const float* __restrict__ in,
                                                     bf16_t* __restrict__ out, int R, int C){
  __shared__ float tile[32][33];
  size_t mb = (size_t)blockIdx.z * R * C;
  int c0 = blockIdx.x*32, r0 = blockIdx.y*32;
  int tx = threadIdx.x, ty = threadIdx.y;
  #pragma unroll
  for (int i = ty; i < 32; i += 8)
    tile[i][tx] = in[mb + (size_t)(r0+i)*C + c0 + tx];
  __syncthreads();
  #pragma unroll
  for (int i = ty; i < 32; i += 8)
    out[mb + (size_t)(c0+i)*R + r0 + tx] = f2bf(tile[tx][i]);
}

// ---- K1: fused dual GEMM: Y = gelu(X@Wy + by), U0 = X@Wx + bx. (round-6 form) ----
__global__ void __launch_bounds__(256,2) gemm_xw_kernel(
    const bf16_t* __restrict__ X,
    const bf16_t* __restrict__ WyT, const bf16_t* __restrict__ WxT, // [N=1024][K=1024]
    const float* __restrict__ by,  const float* __restrict__ bx,
    bf16_t* __restrict__ Y, bf16_t* __restrict__ U0)
{
  __shared__ __align__(16) bf16_t As [128*32];
  __shared__ __align__(16) bf16_t Bys[128*32];
  __shared__ __align__(16) bf16_t Bxs[128*32];
  __shared__ __align__(16) bf16_t scr_g[4][1280];   // per-wave epilogue bounce
  const int K = W_;
  int tid = threadIdx.x, wave = tid>>6, lane = tid&63;
  int wm = wave>>1, wn = wave&1, q = lane>>4, ml = lane&15;
  int lin = blockIdx.x;                    // 2048 blocks, bijective XCD swizzle
  int nl = (lin & 7)*256 + (lin >> 3);
  int bm = nl >> 3, j = nl & 7;
  const bf16_t* Wyp = WyT + (size_t)j*128*K;
  const bf16_t* Wxp = WxT + (size_t)j*128*K;
  f32x4 accY[4][4] = {}, accX[4][4] = {};
  for (int k0 = 0; k0 < K; k0 += 32){
    stage_tile(X + (size_t)bm*128*K + k0, K, As, wave, lane);
    stage_tile(Wyp + k0, K, Bys, wave, lane);
    stage_tile(Wxp + k0, K, Bxs, wave, lane);
    __syncthreads();
    bf16x8 af[4], bvy[4], bvx[4];
    #pragma unroll
    for (int i=0;i<4;i++) af[i]  = *(const bf16x8*)(As  + (wm*64 + i*16 + ml)*32 + q*8);
    #pragma unroll
    for (int i=0;i<4;i++) bvy[i] = *(const bf16x8*)(Bys + (wn*64 + i*16 + ml)*32 + q*8);
    #pragma unroll
    for (int i=0;i<4;i++) bvx[i] = *(const bf16x8*)(Bxs + (wn*64 + i*16 + ml)*32 + q*8);
    #pragma unroll
    for (int i=0;i<4;i++)
      #pragma unroll
      for (int n=0;n<4;n++){
        accY[i][n] = __builtin_amdgcn_mfma_f32_16x16x32_bf16(af[i], bvy[n], accY[i][n], 0,0,0);
        accX[i][n] = __builtin_amdgcn_mfma_f32_16x16x32_bf16(af[i], bvx[n], accX[i][n], 0,0,0);
      }
    __syncthreads();
  }
  float bbY[4], bbX[4];
  #pragma unroll
  for (int n=0;n<4;n++){
    int col = j*128 + wn*64 + n*16 + ml;
    bbY[n] = by[col]; bbX[n] = bx[col];
  }
  bf16_t* s0 = scr_g[wave];
  bf16_t* s1 = s0 + 640;
  int rrow = lane>>2, cgp = lane&3;
  size_t mbase = (size_t)bm*128 + wm*64;
  #pragma unroll
  for (int i=0;i<4;i++){
    size_t grow = mbase + i*16 + rrow;
    int gc = j*128 + wn*64 + cgp*8;
    // Y (gelu)
    #pragma unroll
    for (int n=0;n<4;n++){
      bf16_t* sp = (n<2) ? s0 : s1;
      #pragma unroll
      for (int r=0;r<4;r++)
        sp[(q*4+r)*40 + (n&1)*16 + ml] = f2bf(gelu_fast(accY[i][n][r] + bbY[n]));
    }
    {
      bf16x8 v0 = *(const bf16x8*)(s0 + rrow*40 + cgp*8);
      bf16x8 v1 = *(const bf16x8*)(s1 + rrow*40 + cgp*8);
      *(bf16x8*)(Y + grow*L_ + gc)      = v0;
      *(bf16x8*)(Y + grow*L_ + gc + 32) = v1;
    }
    // U0 (linear) -- reuse scratch; in-wave LDS ordering makes this safe
    #pragma unroll
    for (int n=0;n<4;n++){
      bf16_t* sp = (n<2) ? s0 : s1;
      #pragma unroll
      for (int r=0;r<4;r++)
        sp[(q*4+r)*40 + (n&1)*16 + ml] = f2bf(accX[i][n][r] + bbX[n]);
    }
    {
      bf16x8 v0 = *(const bf16x8*)(s0 + rrow*40 + cgp*8);
      bf16x8 v1 = *(const bf16x8*)(s1 + rrow*40 + cgp*8);
      *(bf16x8*)(U0 + grow*L_ + gc)      = v0;
      *(bf16x8*)(U0 + grow*L_ + gc + 32) = v1;
    }
  }
}

// ---- K3: conv(U0) fused + per-head gate GEMMs + RG-LRU prep + FUSED scan1.
//      64-row x 128-col tiles: per wave 64 acc regs -> (256,3) = 12 waves/CU.
//      As padded to stride 40 (conv writes via VALU, padding legal): kills the
//      8-way epilogue bank conflict. Chunk summary = block's 64 rows:
//      4-row serial runs + ordered q-butterfly + serial i-chain.
__global__ void __launch_bounds__(256,3) gate_kernel(
    const bf16_t* __restrict__ U0,
    const bf16_t* __restrict__ igTw, const bf16_t* __restrict__ agTw, // [H][e=128][d=128]
    const float* __restrict__ igb,  const float* __restrict__ agb,    // [H*128]
    const float* __restrict__ a_param,
    const float* __restrict__ conv_w, const float* __restrict__ conv_b,
    bf16_t* __restrict__ XN, bf16_t* __restrict__ L2A,
    float* __restrict__ Aarr, float* __restrict__ Barr)
{
  __shared__ __align__(16) bf16_t As[4*64*40];      // [kc][row 64][stride 40]
  __shared__ __align__(16) bf16_t scr_g[4][1280];   // per-wave: xn(640), la(640)
  int tid = threadIdx.x, wave = tid>>6, lane = tid&63;
  int wn = wave, q = lane>>4, ml = lane&15;
  int bm = blockIdx.x, h = blockIdx.y;              // bm: 64-row tile = one chunk
  bool first = (bm & 127) == 0;                     // tile starts at segment pos 0

  // ---- Phase 0: conv(U0) -> As (each thread: 4 rows x 8 cols, sliding window) ----
  {
    int cg = tid & 15, rg = tid >> 4;
    int col = cg*8;                 // within head slice (0..120)
    int kcc = col >> 5, c32 = col & 31;
    int r0 = rg*4;
    const bf16_t* up = U0 + ((size_t)bm*64 + r0)*L_ + h*128 + col;
    f32x4 wta[4], wtb[4];
    #pragma unroll
    for (int s=0;s<4;s++){          // tap delay s uses weight conv_w[3-s]
      wta[s] = *(const f32x4*)(conv_w + (size_t)(3-s)*L_ + h*128 + col);
      wtb[s] = *(const f32x4*)(conv_w + (size_t)(3-s)*L_ + h*128 + col + 4);
    }
    f32x4 cba = *(const f32x4*)(conv_b + h*128 + col);
    f32x4 cbb = *(const f32x4*)(conv_b + h*128 + col + 4);
    bf16x8 zero8 = {};
    bf16x8 m1 = (!first || r0 >= 1) ? *(const bf16x8*)(up - 1*L_) : zero8;
    bf16x8 m2 = (!first || r0 >= 2) ? *(const bf16x8*)(up - 2*L_) : zero8;
    bf16x8 m3 = (!first || r0 >= 3) ? *(const bf16x8*)(up - 3*L_) : zero8;
    #pragma unroll
    for (int r=0;r<4;r++){
      bf16x8 cur = *(const bf16x8*)(up + (size_t)r*L_);
      bf16x8 ov;
      #pragma unroll
      for (int e=0;e<4;e++){
        float v0 = cba[e] + bf2f(cur[e])*wta[0][e] + bf2f(m1[e])*wta[1][e]
                          + bf2f(m2[e])*wta[2][e] + bf2f(m3[e])*wta[3][e];
        float v1 = cbb[e] + bf2f(cur[4+e])*wtb[0][e] + bf2f(m1[4+e])*wtb[1][e]
                          + bf2f(m2[4+e])*wtb[2][e] + bf2f(m3[4+e])*wtb[3][e];
        ov[e] = f2bf(v0); ov[4+e] = f2bf(v1);
      }
      *(bf16x8*)(As + kcc*2560 + (size_t)(r0+r)*40 + c32) = ov;
      m3 = m2; m2 = m1; m1 = cur;
    }
  }
  __syncthreads();

  // ---- MFMA: A from LDS (stride 40), B fragments direct from L2-resident weights ----
  const bf16_t* igp = igTw + (size_t)h*D_*D_;
  const bf16_t* agp = agTw + (size_t)h*D_*D_;
  f32x4 ax[4][2] = {}, aa[4][2] = {};
  #pragma unroll
  for (int kc=0; kc<4; ++kc){
    bf16x8 af[4], bx_[2], ba_[2];
    #pragma unroll
    for (int i=0;i<4;i++) af[i]  = *(const bf16x8*)(As + kc*2560 + (i*16 + ml)*40 + q*8);
    #pragma unroll
    for (int n=0;n<2;n++) bx_[n] = *(const bf16x8*)(igp + (size_t)(wn*32 + n*16 + ml)*128 + kc*32 + q*8);
    #pragma unroll
    for (int n=0;n<2;n++) ba_[n] = *(const bf16x8*)(agp + (size_t)(wn*32 + n*16 + ml)*128 + kc*32 + q*8);
    #pragma unroll
    for (int i=0;i<4;i++)
      #pragma unroll
      for (int n=0;n<2;n++){
        ax[i][n] = __builtin_amdgcn_mfma_f32_16x16x32_bf16(af[i], bx_[n], ax[i][n], 0,0,0);
        aa[i][n] = __builtin_amdgcn_mfma_f32_16x16x32_bf16(af[i], ba_[n], aa[i][n], 0,0,0);
      }
  }

  // ---- Epilogue: gates + RG-LRU prep, paired stores, chunk-scan accumulate ----
  bf16_t* sx = scr_g[wave];
  bf16_t* sa = sx + 640;
  int rrow = lane>>2, cgp = lane&3;
  float bb_x[2], bb_a[2], spa2[2];
  #pragma unroll
  for (int n=0;n<2;n++){
    int l = h*D_ + wn*32 + n*16 + ml;
    bb_x[n] = igb[l]; bb_a[n] = agb[l]; spa2[n] = softplus_fast(a_param[l]);
  }
  float runS[4][2], runB[4][2];   // per-thread 4-row run summaries [i][n]
  #pragma unroll
  for (int i=0;i<4;i++){
    #pragma unroll
    for (int r=0;r<4;r++){
      int rl = i*16 + q*4 + r;                       // row within chunk
      bool reset = first && (rl == 0);
      #pragma unroll
      for (int n=0;n<2;n++){
        float uval = bf2f(As[wn*2560 + rl*40 + n*16 + ml]);  // c32 = n*16+ml, kc = wn
        float gx = sigmoid_fast(ax[i][n][r] + bb_x[n]);
        float ga = sigmoid_fast(aa[i][n][r] + bb_a[n]);
        float l2a = -11.541560327111707f * ga * spa2[n];     // -8*log2(e)*ga*spa
        float mult = reset ? 1.0f : sqrt_(fmaxf(0.0f, 1.0f - exp2_(2.0f*l2a)));
        bf16_t xnv = f2bf(uval * gx * mult);
        bf16_t lav = f2bf(reset ? -1e30f : l2a);
        int so = (q*4+r)*40 + n*16 + ml;
        sx[so] = xnv; sa[so] = lav;
        // scan-run accumulate (bf16-rounded values: identical to re-reading L2A/XN)
        float lf = bf2f(lav), xf = bf2f(xnv);
        if (r == 0){ runS[i][n] = lf;  runB[i][n] = xf; }
        else       { runS[i][n] += lf; runB[i][n] = exp2_(lf)*runB[i][n] + xf; }
      }
    }
    size_t grow = (size_t)bm*64 + i*16 + rrow;
    int gcol = h*D_ + wn*32 + cgp*8;
    *(bf16x8*)(XN  + grow*L_ + gcol) = *(const bf16x8*)(sx + rrow*40 + cgp*8);
    *(bf16x8*)(L2A + grow*L_ + gcol) = *(const bf16x8*)(sa + rrow*40 + cgp*8);
  }

  // ---- fused scan1: ordered butterfly across q (lane bits 4,5), serial i-chain ----
  int u16 = lane & 16, u32b = lane & 32;
  float totS[2], totB[2];
  #pragma unroll
  for (int n=0;n<2;n++){
    #pragma unroll
    for (int i=0;i<4;i++){
      float s = runS[i][n], b = runB[i][n];
      float s2 = __shfl_xor(s, 16), b2 = __shfl_xor(b, 16);
      float b1 = u16 ? (exp2_(s)*b2 + b) : (exp2_(s2)*b + b2);   // ordered combine
      float s1 = s + s2;
      float s3 = __shfl_xor(s1, 32), b3 = __shfl_xor(b1, 32);
      float bb = u32b ? (exp2_(s1)*b3 + b1) : (exp2_(s3)*b1 + b3);
      float ss = s1 + s3;
      if (i == 0){ totS[n] = ss; totB[n] = bb; }
      else { totB[n] = exp2_(ss)*totB[n] + bb; totS[n] += ss; }
    }
  }
  if (lane < 16){
    int bb_ = bm >> 7;                   // batch
    int cc_ = bm & 127;                  // chunk within batch
    size_t ci = ((size_t)bb_*NCH_ + cc_)*L_ + h*D_ + wn*32 + ml;
    #pragma unroll
    for (int n=0;n<2;n++){
      Aarr[ci + n*16] = exp2_(totS[n]);
      Barr[ci + n*16] = totB[n];
    }
  }
}

// ---- K5/K6: inter-chunk scan + elementwise apply ----
__global__ void __launch_bounds__(64) scan2_kernel(const float* __restrict__ Aarr,
    const float* __restrict__ Barr, float* __restrict__ Carr)
{
  int l4 = blockIdx.x*64 + threadIdx.x;  // quad index 0..255
  int b = blockIdx.y;
  f32x4 h = {0.f, 0.f, 0.f, 0.f};
  #pragma unroll 4
  for (int c = 0; c < NCH_; ++c){
    size_t ci = ((size_t)b*NCH_ + c)*L_ + (size_t)l4*4;
    f32x4 a  = *(const f32x4*)(Aarr + ci);
    f32x4 bb = *(const f32x4*)(Barr + ci);
    *(f32x4*)(Carr + ci) = h;
    #pragma unroll
    for (int e=0;e<4;e++) h[e] = a[e]*h[e] + bb[e];
  }
}

// one chunk per 256-thread block, 4 channels/thread -> 512 blocks, 8 waves/CU of MLP
__global__ void __launch_bounds__(256) scan3_kernel(const bf16_t* __restrict__ L2A,
    const bf16_t* __restrict__ XN, const bf16_t* __restrict__ Y,
    const float* __restrict__ Carr, bf16_t* __restrict__ HY)
{
  int l = threadIdx.x*4;
  int c = blockIdx.y, b = blockIdx.z;
  size_t base = ((size_t)b*T_ + (size_t)c*CHUNK_)*L_ + l;
  size_t ci = ((size_t)b*NCH_ + c)*L_ + l;
  f32x4 hv = *(const f32x4*)(Carr + ci);
  float h[4];
  #pragma unroll
  for (int e=0;e<4;e++) h[e] = hv[e];
  #pragma unroll 4
  for (int t = 0; t < CHUNK_; ++t){
    bf16x4 la = *(const bf16x4*)(L2A + base + (size_t)t*L_);
    bf16x4 xv = *(const bf16x4*)(XN  + base + (size_t)t*L_);
    bf16x4 yv = *(const bf16x4*)(Y   + base + (size_t)t*L_);
    bf16x4 o;
    #pragma unroll
    for (int e=0;e<4;e++){
      h[e] = exp2_(bf2f(la[e]))*h[e] + bf2f(xv[e]);
      o[e] = f2bf(h[e]*bf2f(yv[e]));
    }
    *(bf16x4*)(HY + base + (size_t)t*L_) = o;
  }
}

// ---- K7: out = HY @ Wout + bout (f32 output), coalesced f32x4 epilogue ----
__global__ void __launch_bounds__(256,2) gemm_out_kernel(
    const bf16_t* __restrict__ A_, const bf16_t* __restrict__ WoT, // [N=1024][K=1024]
    const float* __restrict__ bo, float* __restrict__ Out)
{
  __shared__ __align__(16) bf16_t As[128*32];
  __shared__ __align__(16) bf16_t Bs[128*32];
  __shared__ __align__(16) char scr_[4][1280];
  const int K = L_;
  int tid = threadIdx.x, wave = tid>>6, lane = tid&63;
  int wm = wave>>1, wn = wave&1, q = lane>>4, ml = lane&15;
  int lin = blockIdx.x;                    // 2048 blocks, bijective XCD swizzle
  int nl = (lin & 7)*256 + (lin >> 3);
  int bm = nl >> 3, j = nl & 7;
  const bf16_t* Bp = WoT + (size_t)j*128*K;
  f32x4 acc[4][4] = {};
  for (int k0 = 0; k0 < K; k0 += 32){
    stage_tile(A_ + (size_t)bm*128*K + k0, K, As, wave, lane);
    stage_tile(Bp + k0, K, Bs, wave, lane);
    __syncthreads();
    bf16x8 af[4], bv[4];
    #pragma unroll
    for (int i=0;i<4;i++) af[i] = *(const bf16x8*)(As + (wm*64 + i*16 + ml)*32 + q*8);
    #pragma unroll
    for (int i=0;i<4;i++) bv[i] = *(const bf16x8*)(Bs + (wn*64 + i*16 + ml)*32 + q*8);
    #pragma unroll
    for (int i=0;i<4;i++)
      #pragma unroll
      for (int n=0;n<4;n++)
        acc[i][n] = __builtin_amdgcn_mfma_f32_16x16x32_bf16(af[i], bv[n], acc[i][n], 0,0,0);
    __syncthreads();
  }
  float bb[4];
  #pragma unroll
  for (int n=0;n<4;n++) bb[n] = bo[j*128 + wn*64 + n*16 + ml];
  float* scrf = (float*)scr_[wave];           // 16 rows x stride 20 f32
  int rrow = lane>>2, cgp = lane&3;
  size_t mbase = (size_t)bm*128 + wm*64;
  #pragma unroll
  for (int i=0;i<4;i++){
    size_t grow = mbase + i*16 + rrow;
    #pragma unroll
    for (int n=0;n<4;n++){
      #pragma unroll
      for (int r=0;r<4;r++) scrf[(q*4+r)*20 + ml] = acc[i][n][r] + bb[n];
      f32x4 ov = *(const f32x4*)(scrf + rrow*20 + cgp*4);
      *(f32x4*)(Out + grow*W_ + j*128 + wn*64 + n*16 + cgp*4) = ov;
    }
  }
}

extern "C" void kernel_launch(void* const* d_in, const int* in_sizes, int n_in,
                              void* d_out, int out_size, void* d_ws, size_t ws_size,
                              hipStream_t stream)
{
  (void)in_sizes; (void)n_in; (void)out_size;
  const float* x      = (const float*)d_in[0];
  const float* Wy     = (const float*)d_in[2];
  const float* by     = (const float*)d_in[3];
  const float* Wx     = (const float*)d_in[4];
  const float* bx     = (const float*)d_in[5];
  const float* conv_w = (const float*)d_in[6];
  const float* conv_b = (const float*)d_in[7];
  const float* a_par  = (const float*)d_in[8];
  const float* igw    = (const float*)d_in[9];
  const float* igb    = (const float*)d_in[10];
  const float* agw    = (const float*)d_in[11];
  const float* agb    = (const float*)d_in[12];
  const float* Wout   = (const float*)d_in[13];
  const float* bout   = (const float*)d_in[14];
  float* out = (float*)d_out;

  char* ws = (char*)d_ws;
  size_t off = 0;
  auto alloc = [&](size_t bytes)->void*{ void* p = ws + off; off += (bytes + 255) & ~(size_t)255; return p; };
  bf16_t* Xbf  = (bf16_t*)alloc((size_t)BT_*W_*2);      // x in bf16; dead after gemm_xw
  bf16_t* WyT  = (bf16_t*)alloc((size_t)W_*L_*2);
  bf16_t* WxT  = (bf16_t*)alloc((size_t)W_*L_*2);
  bf16_t* WoT  = (bf16_t*)alloc((size_t)L_*W_*2);
  bf16_t* igTw = (bf16_t*)alloc((size_t)H_*D_*D_*2);
  bf16_t* agTw = (bf16_t*)alloc((size_t)H_*D_*D_*2);
  bf16_t* Y    = (bf16_t*)alloc((size_t)BT_*L_*2);
  bf16_t* U0   = (bf16_t*)alloc((size_t)BT_*L_*2);      // reused as HY after scan3
  bf16_t* XN   = (bf16_t*)alloc((size_t)BT_*L_*2);
  float*  Aarr = (float*) alloc((size_t)B_*NCH_*L_*4);
  float*  Barr = (float*) alloc((size_t)B_*NCH_*L_*4);
  float*  Carr = (float*) alloc((size_t)B_*NCH_*L_*4);
  if (ws_size < off) return;  // insufficient workspace: output stays zero (diagnosable)

  bf16_t* L2A = Xbf;   // alias: Xbf dead once gemm_xw completes, before gate_kernel
  bf16_t* HY  = U0;    // alias: U0 last read by gate_kernel (conv fused there)

  cvt_kernel<<<dim3(BT_*W_/8/256), 256, 0, stream>>>(x, Xbf, BT_*W_/8);

  dim3 tb(32, 8);
  transpose_f2b<<<dim3(32,32,1), tb, 0, stream>>>(Wy,   WyT, 1024, 1024);
  transpose_f2b<<<dim3(32,32,1), tb, 0, stream>>>(Wx,   WxT, 1024, 1024);
  transpose_f2b<<<dim3(32,32,1), tb, 0, stream>>>(Wout, WoT, 1024, 1024);
  transpose_f2b<<<dim3(4,4,H_),  tb, 0, stream>>>(igw,  igTw, 128, 128);
  transpose_f2b<<<dim3(4,4,H_),  tb, 0, stream>>>(agw,  agTw, 128, 128);

  gemm_xw_kernel<<<dim3(2048), 256, 0, stream>>>(Xbf, WyT, WxT, by, bx, Y, U0);
  gate_kernel<<<dim3(BT_/64, H_), 256, 0, stream>>>(U0, igTw, agTw, igb, agb, a_par,
                                                    conv_w, conv_b, XN, L2A, Aarr, Barr);
  scan2_kernel<<<dim3(4, B_), 64, 0, stream>>>(Aarr, Barr, Carr);
  scan3_kernel<<<dim3(1, NCH_, B_), 256, 0, stream>>>(L2A, XN, Y, Carr, HY);
  gemm_out_kernel<<<dim3(2048), 256, 0, stream>>>(HY, WoT, bout, out);
}

// Round 9
// 640.898 us; speedup vs baseline: 1.0440x; 1.0125x over previous
//
#include <hip/hip_runtime.h>
#include <cstdint>
#include <cstddef>

// ---- problem dims ----
#define B_ 4
#define T_ 8192
#define W_ 1024
#define L_ 1024
#define H_ 8
#define D_ 128
#define TW_ 4
#define BT_ (B_*T_)        // 32768 rows
#define CHUNK_ 64
#define NCH_ (T_/CHUNK_)   // 128 chunks

typedef __bf16 bf16_t;
typedef __bf16 bf16x8 __attribute__((ext_vector_type(8)));
typedef __bf16 bf16x4 __attribute__((ext_vector_type(4)));
typedef float  f32x4  __attribute__((ext_vector_type(4)));

__device__ __forceinline__ float  bf2f(bf16_t x){ return (float)x; }
__device__ __forceinline__ bf16_t f2bf(float x){ return (bf16_t)x; }

// raw-instruction transcendentals (avoid libm IEEE fixup sequences; outputs are bf16)
__device__ __forceinline__ float rcp_ (float x){ return __builtin_amdgcn_rcpf(x); }
__device__ __forceinline__ float sqrt_(float x){ return __builtin_amdgcn_sqrtf(x); }
__device__ __forceinline__ float exp2_(float x){ return __builtin_amdgcn_exp2f(x); }
__device__ __forceinline__ float log2_(float x){ return __builtin_amdgcn_logf(x); }
#define LOG2E_ 1.4426950408889634f

__device__ __forceinline__ float sigmoid_fast(float z){
  return rcp_(1.0f + exp2_(-LOG2E_*z));
}
__device__ __forceinline__ float softplus_fast(float x){
  return (x > 15.0f) ? x : 0.6931471805599453f * log2_(1.0f + exp2_(LOG2E_*x));
}
__device__ __forceinline__ float gelu_fast(float z){
  float g = 0.7978845608028654f*(z + 0.044715f*z*z*z);
  float e = exp2_(-2.8853900817779268f*fabsf(g));   // exp(-2|g|)
  float th = (1.0f - e)*rcp_(1.0f + e);
  th = copysignf(th, g);
  return 0.5f*z*(1.0f + th);
}

// ---- async global->LDS staging: 128-row x 32-col bf16 tile, row-major, no pad ----
__device__ __forceinline__ void stage16(const bf16_t* g, bf16_t* l){
  __builtin_amdgcn_global_load_lds((const __attribute__((address_space(1))) void*)g,
                                   (__attribute__((address_space(3))) void*)l, 16, 0, 0);
}
__device__ __forceinline__ void stage_tile(const bf16_t* __restrict__ gbase, int ldg,
                                           bf16_t* lds, int wave, int lane){
  #pragma unroll
  for (int c2 = 0; c2 < 2; ++c2){
    int chunk = wave*2 + c2;
    int row = chunk*16 + (lane >> 2);
    int col = (lane & 3)*8;
    stage16(gbase + (size_t)row*ldg + col, lds + chunk*512 + lane*8);
  }
}

// ---- f32 -> bf16 bulk convert (for x) ----
__global__ void __launch_bounds__(256) cvt_kernel(const float* __restrict__ in,
                                                  bf16_t* __restrict__ out, int n8){
  int g = blockIdx.x*256 + threadIdx.x;
  if (g >= n8) return;
  f32x4 a = *(const f32x4*)(in + (size_t)g*8);
  f32x4 b = *(const f32x4*)(in + (size_t)g*8 + 4);
  bf16x8 o;
  #pragma unroll
  for (int e=0;e<4;e++){ o[e] = f2bf(a[e]); o[4+e] = f2bf(b[e]); }
  *(bf16x8*)(out + (size_t)g*8) = o;
}

// ---- batched transpose f32 -> bf16: out[b][c][r] = (bf16)in[b][r][c] ----
__global__ void __launch_bounds__(256) transpose_f2b(const float* __restrict__ in,
                                                     bf16_t* __restrict__ out, int R, int C){
  __shared__ float tile[32][33];
  size_t mb = (size_t)blockIdx.z * R * C;
  int c0 = blockIdx.x*32, r0 = blockIdx.y*32;
  int tx = threadIdx.x, ty = threadIdx.y;
  #pragma unroll
  for (int i = ty; i < 32; i += 8)
    tile[i][tx] = in[mb + (size_t)(r0+i)*C + c0 + tx];
  __syncthreads();
  #pragma unroll
  for (int i = ty; i < 32; i += 8)
    out[mb + (size_t)(c0+i)*R + r0 + tx] = f2bf(tile[tx][i]);
}

// ---- K1: fused dual GEMM: Y = gelu(X@Wy + by), U0 = X@Wx + bx.
//      BK=64: two 32-col sub-chunks staged per barrier pair -> 16 drains not 32.
//      Coalesced LDS-bounce epilogue with full-line (128B) store pairs.
__global__ void __launch_bounds__(256,2) gemm_xw_kernel(
    const bf16_t* __restrict__ X,
    const bf16_t* __restrict__ WyT, const bf16_t* __restrict__ WxT, // [N=1024][K=1024]
    const float* __restrict__ by,  const float* __restrict__ bx,
    bf16_t* __restrict__ Y, bf16_t* __restrict__ U0)
{
  __shared__ __align__(16) bf16_t As [2][128*32];
  __shared__ __align__(16) bf16_t Bys[2][128*32];
  __shared__ __align__(16) bf16_t Bxs[2][128*32];
  __shared__ __align__(16) bf16_t scr_g[4][1280];   // per-wave epilogue bounce
  const int K = W_;
  int tid = threadIdx.x, wave = tid>>6, lane = tid&63;
  int wm = wave>>1, wn = wave&1, q = lane>>4, ml = lane&15;
  int lin = blockIdx.x;                    // 2048 blocks, bijective XCD swizzle
  int nl = (lin & 7)*256 + (lin >> 3);
  int bm = nl >> 3, j = nl & 7;
  const bf16_t* Xp  = X   + (size_t)bm*128*K;
  const bf16_t* Wyp = WyT + (size_t)j*128*K;
  const bf16_t* Wxp = WxT + (size_t)j*128*K;
  f32x4 accY[4][4] = {}, accX[4][4] = {};
  for (int k0 = 0; k0 < K; k0 += 64){
    #pragma unroll
    for (int s=0;s<2;s++){
      stage_tile(Xp  + k0 + s*32, K, As [s], wave, lane);
      stage_tile(Wyp + k0 + s*32, K, Bys[s], wave, lane);
      stage_tile(Wxp + k0 + s*32, K, Bxs[s], wave, lane);
    }
    __syncthreads();
    #pragma unroll
    for (int s=0;s<2;s++){
      bf16x8 af[4], bvy[4], bvx[4];
      #pragma unroll
      for (int i=0;i<4;i++) af[i]  = *(const bf16x8*)(As [s] + (wm*64 + i*16 + ml)*32 + q*8);
      #pragma unroll
      for (int i=0;i<4;i++) bvy[i] = *(const bf16x8*)(Bys[s] + (wn*64 + i*16 + ml)*32 + q*8);
      #pragma unroll
      for (int i=0;i<4;i++) bvx[i] = *(const bf16x8*)(Bxs[s] + (wn*64 + i*16 + ml)*32 + q*8);
      #pragma unroll
      for (int i=0;i<4;i++)
        #pragma unroll
        for (int n=0;n<4;n++){
          accY[i][n] = __builtin_amdgcn_mfma_f32_16x16x32_bf16(af[i], bvy[n], accY[i][n], 0,0,0);
          accX[i][n] = __builtin_amdgcn_mfma_f32_16x16x32_bf16(af[i], bvx[n], accX[i][n], 0,0,0);
        }
    }
    __syncthreads();
  }
  float bbY[4], bbX[4];
  #pragma unroll
  for (int n=0;n<4;n++){
    int col = j*128 + wn*64 + n*16 + ml;
    bbY[n] = by[col]; bbX[n] = bx[col];
  }
  bf16_t* s0 = scr_g[wave];
  bf16_t* s1 = s0 + 640;
  int rrow = lane>>2, cgp = lane&3;
  size_t mbase = (size_t)bm*128 + wm*64;
  #pragma unroll
  for (int i=0;i<4;i++){
    size_t grow = mbase + i*16 + rrow;
    int gc = j*128 + wn*64 + cgp*8;
    // Y (gelu)
    #pragma unroll
    for (int n=0;n<4;n++){
      bf16_t* sp = (n<2) ? s0 : s1;
      #pragma unroll
      for (int r=0;r<4;r++)
        sp[(q*4+r)*40 + (n&1)*16 + ml] = f2bf(gelu_fast(accY[i][n][r] + bbY[n]));
    }
    {
      bf16x8 v0 = *(const bf16x8*)(s0 + rrow*40 + cgp*8);
      bf16x8 v1 = *(const bf16x8*)(s1 + rrow*40 + cgp*8);
      *(bf16x8*)(Y + grow*L_ + gc)      = v0;
      *(bf16x8*)(Y + grow*L_ + gc + 32) = v1;
    }
    // U0 (linear) -- reuse scratch; in-wave LDS ordering makes this safe
    #pragma unroll
    for (int n=0;n<4;n++){
      bf16_t* sp = (n<2) ? s0 : s1;
      #pragma unroll
      for (int r=0;r<4;r++)
        sp[(q*4+r)*40 + (n&1)*16 + ml] = f2bf(accX[i][n][r] + bbX[n]);
    }
    {
      bf16x8 v0 = *(const bf16x8*)(s0 + rrow*40 + cgp*8);
      bf16x8 v1 = *(const bf16x8*)(s1 + rrow*40 + cgp*8);
      *(bf16x8*)(U0 + grow*L_ + gc)      = v0;
      *(bf16x8*)(U0 + grow*L_ + gc + 32) = v1;
    }
  }
}

// ---- K3: conv(U0) fused + per-head gate GEMMs + RG-LRU prep + FUSED scan1.
//      64-row x 128-col tiles: per wave 64 acc regs -> (256,3) = 12 waves/CU.
//      As padded to stride 40 (conv writes via VALU, padding legal).
__global__ void __launch_bounds__(256,3) gate_kernel(
    const bf16_t* __restrict__ U0,
    const bf16_t* __restrict__ igTw, const bf16_t* __restrict__ agTw, // [H][e=128][d=128]
    const float* __restrict__ igb,  const float* __restrict__ agb,    // [H*128]
    const float* __restrict__ a_param,
    const float* __restrict__ conv_w, const float* __restrict__ conv_b,
    bf16_t* __restrict__ XN, bf16_t* __restrict__ L2A,
    float* __restrict__ Aarr, float* __restrict__ Barr)
{
  __shared__ __align__(16) bf16_t As[4*64*40];      // [kc][row 64][stride 40]
  __shared__ __align__(16) bf16_t scr_g[4][1280];   // per-wave: xn(640), la(640)
  int tid = threadIdx.x, wave = tid>>6, lane = tid&63;
  int wn = wave, q = lane>>4, ml = lane&15;
  int bm = blockIdx.x, h = blockIdx.y;              // bm: 64-row tile = one chunk
  bool first = (bm & 127) == 0;                     // tile starts at segment pos 0

  // ---- Phase 0: conv(U0) -> As (each thread: 4 rows x 8 cols, sliding window) ----
  {
    int cg = tid & 15, rg = tid >> 4;
    int col = cg*8;                 // within head slice (0..120)
    int kcc = col >> 5, c32 = col & 31;
    int r0 = rg*4;
    const bf16_t* up = U0 + ((size_t)bm*64 + r0)*L_ + h*128 + col;
    f32x4 wta[4], wtb[4];
    #pragma unroll
    for (int s=0;s<4;s++){          // tap delay s uses weight conv_w[3-s]
      wta[s] = *(const f32x4*)(conv_w + (size_t)(3-s)*L_ + h*128 + col);
      wtb[s] = *(const f32x4*)(conv_w + (size_t)(3-s)*L_ + h*128 + col + 4);
    }
    f32x4 cba = *(const f32x4*)(conv_b + h*128 + col);
    f32x4 cbb = *(const f32x4*)(conv_b + h*128 + col + 4);
    bf16x8 zero8 = {};
    bf16x8 m1 = (!first || r0 >= 1) ? *(const bf16x8*)(up - 1*L_) : zero8;
    bf16x8 m2 = (!first || r0 >= 2) ? *(const bf16x8*)(up - 2*L_) : zero8;
    bf16x8 m3 = (!first || r0 >= 3) ? *(const bf16x8*)(up - 3*L_) : zero8;
    #pragma unroll
    for (int r=0;r<4;r++){
      bf16x8 cur = *(const bf16x8*)(up + (size_t)r*L_);
      bf16x8 ov;
      #pragma unroll
      for (int e=0;e<4;e++){
        float v0 = cba[e] + bf2f(cur[e])*wta[0][e] + bf2f(m1[e])*wta[1][e]
                          + bf2f(m2[e])*wta[2][e] + bf2f(m3[e])*wta[3][e];
        float v1 = cbb[e] + bf2f(cur[4+e])*wtb[0][e] + bf2f(m1[4+e])*wtb[1][e]
                          + bf2f(m2[4+e])*wtb[2][e] + bf2f(m3[4+e])*wtb[3][e];
        ov[e] = f2bf(v0); ov[4+e] = f2bf(v1);
      }
      *(bf16x8*)(As + kcc*2560 + (size_t)(r0+r)*40 + c32) = ov;
      m3 = m2; m2 = m1; m1 = cur;
    }
  }
  __syncthreads();

  // ---- MFMA: A from LDS (stride 40), B fragments direct from L2-resident weights ----
  const bf16_t* igp = igTw + (size_t)h*D_*D_;
  const bf16_t* agp = agTw + (size_t)h*D_*D_;
  f32x4 ax[4][2] = {}, aa[4][2] = {};
  #pragma unroll
  for (int kc=0; kc<4; ++kc){
    bf16x8 af[4], bx_[2], ba_[2];
    #pragma unroll
    for (int i=0;i<4;i++) af[i]  = *(const bf16x8*)(As + kc*2560 + (i*16 + ml)*40 + q*8);
    #pragma unroll
    for (int n=0;n<2;n++) bx_[n] = *(const bf16x8*)(igp + (size_t)(wn*32 + n*16 + ml)*128 + kc*32 + q*8);
    #pragma unroll
    for (int n=0;n<2;n++) ba_[n] = *(const bf16x8*)(agp + (size_t)(wn*32 + n*16 + ml)*128 + kc*32 + q*8);
    #pragma unroll
    for (int i=0;i<4;i++)
      #pragma unroll
      for (int n=0;n<2;n++){
        ax[i][n] = __builtin_amdgcn_mfma_f32_16x16x32_bf16(af[i], bx_[n], ax[i][n], 0,0,0);
        aa[i][n] = __builtin_amdgcn_mfma_f32_16x16x32_bf16(af[i], ba_[n], aa[i][n], 0,0,0);
      }
  }

  // ---- Epilogue: gates + RG-LRU prep, paired stores, chunk-scan accumulate ----
  bf16_t* sx = scr_g[wave];
  bf16_t* sa = sx + 640;
  int rrow = lane>>2, cgp = lane&3;
  float bb_x[2], bb_a[2], spa2[2];
  #pragma unroll
  for (int n=0;n<2;n++){
    int l = h*D_ + wn*32 + n*16 + ml;
    bb_x[n] = igb[l]; bb_a[n] = agb[l]; spa2[n] = softplus_fast(a_param[l]);
  }
  float runS[4][2], runB[4][2];   // per-thread 4-row run summaries [i][n]
  #pragma unroll
  for (int i=0;i<4;i++){
    #pragma unroll
    for (int r=0;r<4;r++){
      int rl = i*16 + q*4 + r;                       // row within chunk
      bool reset = first && (rl == 0);
      #pragma unroll
      for (int n=0;n<2;n++){
        float uval = bf2f(As[wn*2560 + rl*40 + n*16 + ml]);  // c32 = n*16+ml, kc = wn
        float gx = sigmoid_fast(ax[i][n][r] + bb_x[n]);
        float ga = sigmoid_fast(aa[i][n][r] + bb_a[n]);
        float l2a = -11.541560327111707f * ga * spa2[n];     // -8*log2(e)*ga*spa
        float mult = reset ? 1.0f : sqrt_(fmaxf(0.0f, 1.0f - exp2_(2.0f*l2a)));
        bf16_t xnv = f2bf(uval * gx * mult);
        bf16_t lav = f2bf(reset ? -1e30f : l2a);
        int so = (q*4+r)*40 + n*16 + ml;
        sx[so] = xnv; sa[so] = lav;
        // scan-run accumulate (bf16-rounded values: identical to re-reading L2A/XN)
        float lf = bf2f(lav), xf = bf2f(xnv);
        if (r == 0){ runS[i][n] = lf;  runB[i][n] = xf; }
        else       { runS[i][n] += lf; runB[i][n] = exp2_(lf)*runB[i][n] + xf; }
      }
    }
    size_t grow = (size_t)bm*64 + i*16 + rrow;
    int gcol = h*D_ + wn*32 + cgp*8;
    *(bf16x8*)(XN  + grow*L_ + gcol) = *(const bf16x8*)(sx + rrow*40 + cgp*8);
    *(bf16x8*)(L2A + grow*L_ + gcol) = *(const bf16x8*)(sa + rrow*40 + cgp*8);
  }

  // ---- fused scan1: ordered butterfly across q (lane bits 4,5), serial i-chain ----
  int u16 = lane & 16, u32b = lane & 32;
  float totS[2], totB[2];
  #pragma unroll
  for (int n=0;n<2;n++){
    #pragma unroll
    for (int i=0;i<4;i++){
      float s = runS[i][n], b = runB[i][n];
      float s2 = __shfl_xor(s, 16), b2 = __shfl_xor(b, 16);
      float b1 = u16 ? (exp2_(s)*b2 + b) : (exp2_(s2)*b + b2);   // ordered combine
      float s1 = s + s2;
      float s3 = __shfl_xor(s1, 32), b3 = __shfl_xor(b1, 32);
      float bb = u32b ? (exp2_(s1)*b3 + b1) : (exp2_(s3)*b1 + b3);
      float ss = s1 + s3;
      if (i == 0){ totS[n] = ss; totB[n] = bb; }
      else { totB[n] = exp2_(ss)*totB[n] + bb; totS[n] += ss; }
    }
  }
  if (lane < 16){
    int bb_ = bm >> 7;                   // batch
    int cc_ = bm & 127;                  // chunk within batch
    size_t ci = ((size_t)bb_*NCH_ + cc_)*L_ + h*D_ + wn*32 + ml;
    #pragma unroll
    for (int n=0;n<2;n++){
      Aarr[ci + n*16] = exp2_(totS[n]);
      Barr[ci + n*16] = totB[n];
    }
  }
}

// ---- K5/K6: inter-chunk scan + elementwise apply ----
__global__ void __launch_bounds__(64) scan2_kernel(const float* __restrict__ Aarr,
    const float* __restrict__ Barr, float* __restrict__ Carr)
{
  int l4 = blockIdx.x*64 + threadIdx.x;  // quad index 0..255
  int b = blockIdx.y;
  f32x4 h = {0.f, 0.f, 0.f, 0.f};
  #pragma unroll 4
  for (int c = 0; c < NCH_; ++c){
    size_t ci = ((size_t)b*NCH_ + c)*L_ + (size_t)l4*4;
    f32x4 a  = *(const f32x4*)(Aarr + ci);
    f32x4 bb = *(const f32x4*)(Barr + ci);
    *(f32x4*)(Carr + ci) = h;
    #pragma unroll
    for (int e=0;e<4;e++) h[e] = a[e]*h[e] + bb[e];
  }
}

// one chunk per 256-thread block, 4 channels/thread -> 512 blocks, 8 waves/CU of MLP
__global__ void __launch_bounds__(256) scan3_kernel(const bf16_t* __restrict__ L2A,
    const bf16_t* __restrict__ XN, const bf16_t* __restrict__ Y,
    const float* __restrict__ Carr, bf16_t* __restrict__ HY)
{
  int l = threadIdx.x*4;
  int c = blockIdx.y, b = blockIdx.z;
  size_t base = ((size_t)b*T_ + (size_t)c*CHUNK_)*L_ + l;
  size_t ci = ((size_t)b*NCH_ + c)*L_ + l;
  f32x4 hv = *(const f32x4*)(Carr + ci);
  float h[4];
  #pragma unroll
  for (int e=0;e<4;e++) h[e] = hv[e];
  #pragma unroll 4
  for (int t = 0; t < CHUNK_; ++t){
    bf16x4 la = *(const bf16x4*)(L2A + base + (size_t)t*L_);
    bf16x4 xv = *(const bf16x4*)(XN  + base + (size_t)t*L_);
    bf16x4 yv = *(const bf16x4*)(Y   + base + (size_t)t*L_);
    bf16x4 o;
    #pragma unroll
    for (int e=0;e<4;e++){
      h[e] = exp2_(bf2f(la[e]))*h[e] + bf2f(xv[e]);
      o[e] = f2bf(h[e]*bf2f(yv[e]));
    }
    *(bf16x4*)(HY + base + (size_t)t*L_) = o;
  }
}

// ---- K7: out = HY @ Wout + bout (f32 output), BK=64 + coalesced f32x4 epilogue ----
__global__ void __launch_bounds__(256,2) gemm_out_kernel(
    const bf16_t* __restrict__ A_, const bf16_t* __restrict__ WoT, // [N=1024][K=1024]
    const float* __restrict__ bo, float* __restrict__ Out)
{
  __shared__ __align__(16) bf16_t As[2][128*32];
  __shared__ __align__(16) bf16_t Bs[2][128*32];
  __shared__ __align__(16) char scr_[4][1280];
  const int K = L_;
  int tid = threadIdx.x, wave = tid>>6, lane = tid&63;
  int wm = wave>>1, wn = wave&1, q = lane>>4, ml = lane&15;
  int lin = blockIdx.x;                    // 2048 blocks, bijective XCD swizzle
  int nl = (lin & 7)*256 + (lin >> 3);
  int bm = nl >> 3, j = nl & 7;
  const bf16_t* Ap = A_  + (size_t)bm*128*K;
  const bf16_t* Bp = WoT + (size_t)j*128*K;
  f32x4 acc[4][4] = {};
  for (int k0 = 0; k0 < K; k0 += 64){
    #pragma unroll
    for (int s=0;s<2;s++){
      stage_tile(Ap + k0 + s*32, K, As[s], wave, lane);
      stage_tile(Bp + k0 + s*32, K, Bs[s], wave, lane);
    }
    __syncthreads();
    #pragma unroll
    for (int s=0;s<2;s++){
      bf16x8 af[4], bv[4];
      #pragma unroll
      for (int i=0;i<4;i++) af[i] = *(const bf16x8*)(As[s] + (wm*64 + i*16 + ml)*32 + q*8);
      #pragma unroll
      for (int i=0;i<4;i++) bv[i] = *(const bf16x8*)(Bs[s] + (wn*64 + i*16 + ml)*32 + q*8);
      #pragma unroll
      for (int i=0;i<4;i++)
        #pragma unroll
        for (int n=0;n<4;n++)
          acc[i][n] = __builtin_amdgcn_mfma_f32_16x16x32_bf16(af[i], bv[n], acc[i][n], 0,0,0);
    }
    __syncthreads();
  }
  float bb[4];
  #pragma unroll
  for (int n=0;n<4;n++) bb[n] = bo[j*128 + wn*64 + n*16 + ml];
  float* scrf = (float*)scr_[wave];           // 16 rows x stride 20 f32
  int rrow = lane>>2, cgp = lane&3;
  size_t mbase = (size_t)bm*128 + wm*64;
  #pragma unroll
  for (int i=0;i<4;i++){
    size_t grow = mbase + i*16 + rrow;
    #pragma unroll
    for (int n=0;n<4;n++){
      #pragma unroll
      for (int r=0;r<4;r++) scrf[(q*4+r)*20 + ml] = acc[i][n][r] + bb[n];
      f32x4 ov = *(const f32x4*)(scrf + rrow*20 + cgp*4);
      *(f32x4*)(Out + grow*W_ + j*128 + wn*64 + n*16 + cgp*4) = ov;
    }
  }
}

extern "C" void kernel_launch(void* const* d_in, const int* in_sizes, int n_in,
                              void* d_out, int out_size, void* d_ws, size_t ws_size,
                              hipStream_t stream)
{
  (void)in_sizes; (void)n_in; (void)out_size;
  const float* x      = (const float*)d_in[0];
  const float* Wy     = (const float*)d_in[2];
  const float* by     = (const float*)d_in[3];
  const float* Wx     = (const float*)d_in[4];
  const float* bx     = (const float*)d_in[5];
  const float* conv_w = (const float*)d_in[6];
  const float* conv_b = (const float*)d_in[7];
  const float* a_par  = (const float*)d_in[8];
  const float* igw    = (const float*)d_in[9];
  const float* igb    = (const float*)d_in[10];
  const float* agw    = (const float*)d_in[11];
  const float* agb    = (const float*)d_in[12];
  const float* Wout   = (const float*)d_in[13];
  const float* bout   = (const float*)d_in[14];
  float* out = (float*)d_out;

  char* ws = (char*)d_ws;
  size_t off = 0;
  auto alloc = [&](size_t bytes)->void*{ void* p = ws + off; off += (bytes + 255) & ~(size_t)255; return p; };
  bf16_t* Xbf  = (bf16_t*)alloc((size_t)BT_*W_*2);      // x in bf16; dead after gemm_xw
  bf16_t* WyT  = (bf16_t*)alloc((size_t)W_*L_*2);
  bf16_t* WxT  = (bf16_t*)alloc((size_t)W_*L_*2);
  bf16_t* WoT  = (bf16_t*)alloc((size_t)L_*W_*2);
  bf16_t* igTw = (bf16_t*)alloc((size_t)H_*D_*D_*2);
  bf16_t* agTw = (bf16_t*)alloc((size_t)H_*D_*D_*2);
  bf16_t* Y    = (bf16_t*)alloc((size_t)BT_*L_*2);
  bf16_t* U0   = (bf16_t*)alloc((size_t)BT_*L_*2);      // reused as HY after scan3
  bf16_t* XN   = (bf16_t*)alloc((size_t)BT_*L_*2);
  float*  Aarr = (float*) alloc((size_t)B_*NCH_*L_*4);
  float*  Barr = (float*) alloc((size_t)B_*NCH_*L_*4);
  float*  Carr = (float*) alloc((size_t)B_*NCH_*L_*4);
  if (ws_size < off) return;  // insufficient workspace: output stays zero (diagnosable)

  bf16_t* L2A = Xbf;   // alias: Xbf dead once gemm_xw completes, before gate_kernel
  bf16_t* HY  = U0;    // alias: U0 last read by gate_kernel (conv fused there)

  cvt_kernel<<<dim3(BT_*W_/8/256), 256, 0, stream>>>(x, Xbf, BT_*W_/8);

  dim3 tb(32, 8);
  transpose_f2b<<<dim3(32,32,1), tb, 0, stream>>>(Wy,   WyT, 1024, 1024);
  transpose_f2b<<<dim3(32,32,1), tb, 0, stream>>>(Wx,   WxT, 1024, 1024);
  transpose_f2b<<<dim3(32,32,1), tb, 0, stream>>>(Wout, WoT, 1024, 1024);
  transpose_f2b<<<dim3(4,4,H_),  tb, 0, stream>>>(igw,  igTw, 128, 128);
  transpose_f2b<<<dim3(4,4,H_),  tb, 0, stream>>>(agw,  agTw, 128, 128);

  gemm_xw_kernel<<<dim3(2048), 256, 0, stream>>>(Xbf, WyT, WxT, by, bx, Y, U0);
  gate_kernel<<<dim3(BT_/64, H_), 256, 0, stream>>>(U0, igTw, agTw, igb, agb, a_par,
                                                    conv_w, conv_b, XN, L2A, Aarr, Barr);
  scan2_kernel<<<dim3(4, B_), 64, 0, stream>>>(Aarr, Barr, Carr);
  scan3_kernel<<<dim3(1, NCH_, B_), 256, 0, stream>>>(L2A, XN, Y, Carr, HY);
  gemm_out_kernel<<<dim3(2048), 256, 0, stream>>>(HY, WoT, bout, out);
}